// Round 2
// baseline (1011.983 us; speedup 1.0000x reference)
//
#include <hip/hip_runtime.h>
#include <hip/hip_bf16.h>

typedef __bf16 bf16;
typedef __bf16 bf16x2 __attribute__((ext_vector_type(2)));
typedef __bf16 bf16x4 __attribute__((ext_vector_type(4)));
typedef __bf16 bf16x8 __attribute__((ext_vector_type(8)));
typedef float f32x4 __attribute__((ext_vector_type(4)));

#define SEQ 512
#define DIM 512
#define NH 16
#define DH 32
#define FFD 2048
#define NBATCH 32
#define MTOT (NBATCH * SEQ)   // 16384

// ---------------- async global->LDS helper (16B) ----------------
__device__ __forceinline__ void gl_lds16(const bf16* g, bf16* l) {
  __builtin_amdgcn_global_load_lds(
      (const __attribute__((address_space(1))) void*)g,
      (__attribute__((address_space(3))) void*)l, 16, 0, 0);
}

// ---------------- GEMM: A (MxK, bf16) @ BT (NxK, bf16) + bias ----------------
// EPI 0: relu, write to (B,H,S,DH) qkv layout; EPI 1: relu, row-major; EPI 2: row-major.
template <int EPI>
__global__ __launch_bounds__(256, 2)
void gemm_bt(const bf16* __restrict__ A, const bf16* __restrict__ BT,
             const float* __restrict__ bias, bf16* __restrict__ out,
             int N, int K) {
  __shared__ bf16 As[128 * 32];
  __shared__ bf16 Bs[128 * 32];
  const int tid = threadIdx.x;
  const int lane = tid & 63, wave = tid >> 6;
  const int wr = wave >> 1, wc = wave & 1;
  const int lo = lane & 15, hi = lane >> 4;
  const int m0 = blockIdx.y * 128, n0 = blockIdx.x * 128;
  const bf16* Ab = A + (size_t)m0 * K;
  const bf16* Bb = BT + (size_t)n0 * K;
  f32x4 acc[4][4] = {};
  for (int k0 = 0; k0 < K; k0 += 32) {
    __syncthreads();
    {
      const int i0 = tid, i1 = tid + 256;
      gl_lds16(Ab + (size_t)(i0 >> 2) * K + k0 + (i0 & 3) * 8, As + i0 * 8);
      gl_lds16(Ab + (size_t)(i1 >> 2) * K + k0 + (i1 & 3) * 8, As + i1 * 8);
      gl_lds16(Bb + (size_t)(i0 >> 2) * K + k0 + (i0 & 3) * 8, Bs + i0 * 8);
      gl_lds16(Bb + (size_t)(i1 >> 2) * K + k0 + (i1 & 3) * 8, Bs + i1 * 8);
    }
    __syncthreads();  // drains vmcnt+lgkmcnt
    bf16x8 a[4], b[4];
#pragma unroll
    for (int i = 0; i < 4; ++i) {
      a[i] = *(const bf16x8*)(As + (wr * 64 + i * 16 + lo) * 32 + hi * 8);
      b[i] = *(const bf16x8*)(Bs + (wc * 64 + i * 16 + lo) * 32 + hi * 8);
    }
#pragma unroll
    for (int i = 0; i < 4; ++i)
#pragma unroll
      for (int j = 0; j < 4; ++j)
        acc[i][j] = __builtin_amdgcn_mfma_f32_16x16x32_bf16(a[i], b[j], acc[i][j], 0, 0, 0);
  }
#pragma unroll
  for (int i = 0; i < 4; ++i) {
#pragma unroll
    for (int j = 0; j < 4; ++j) {
      const int n = n0 + wc * 64 + j * 16 + lo;
      const float bs = bias[n];
#pragma unroll
      for (int r = 0; r < 4; ++r) {
        const int m = m0 + wr * 64 + i * 16 + hi * 4 + r;
        float v = acc[i][j][r] + bs;
        if (EPI != 2) v = fmaxf(v, 0.f);
        if (EPI == 0) {
          const int b_ = m >> 9, s_ = m & 511, h_ = n >> 5, dh_ = n & 31;
          out[(((size_t)(b_ * NH + h_)) * SEQ + s_) * DH + dh_] = (bf16)v;
        } else {
          out[(size_t)m * N + n] = (bf16)v;
        }
      }
    }
  }
}

// ---------------- fused attention: one block per (b,h) ----------------
__global__ __launch_bounds__(256, 2)
void attn_kernel(const bf16* __restrict__ Qb, const bf16* __restrict__ Kb,
                 const bf16* __restrict__ Vb, bf16* __restrict__ O) {
  __shared__ bf16 Vt[32][520];     // V^T, padded: rows stride 1040B -> 2-way max
  __shared__ bf16 P[4][16][40];    // per-wave P chunk, padded rows 80B
  const int bh = blockIdx.x;
  const int tid = threadIdx.x, lane = tid & 63, wave = tid >> 6;
  const int lo = lane & 15, hi = lane >> 4;
  const bf16* Qp = Qb + (size_t)bh * SEQ * DH;
  const bf16* Kp = Kb + (size_t)bh * SEQ * DH;
  const bf16* Vp = Vb + (size_t)bh * SEQ * DH;
  for (int r = tid; r < SEQ; r += 256) {
    bf16x8 v0 = *(const bf16x8*)(Vp + r * DH);
    bf16x8 v1 = *(const bf16x8*)(Vp + r * DH + 8);
    bf16x8 v2 = *(const bf16x8*)(Vp + r * DH + 16);
    bf16x8 v3 = *(const bf16x8*)(Vp + r * DH + 24);
#pragma unroll
    for (int c = 0; c < 8; ++c) {
      Vt[c][r] = v0[c]; Vt[8 + c][r] = v1[c];
      Vt[16 + c][r] = v2[c]; Vt[24 + c][r] = v3[c];
    }
  }
  __syncthreads();
  const float CEXP = 0.17677669529663687f * 1.44269504088896f;  // scale*log2e
  const int b_ = bh >> 4, h_ = bh & 15;
  for (int chunk = wave; chunk < 32; chunk += 4) {
    const int s0 = chunk * 16;
    bf16x8 qf = *(const bf16x8*)(Qp + (s0 + lo) * DH + hi * 8);
    f32x4 acc[32];
#pragma unroll
    for (int t = 0; t < 32; ++t) {
      bf16x8 kf = *(const bf16x8*)(Kp + (t * 16 + lo) * DH + hi * 8);
      acc[t] = __builtin_amdgcn_mfma_f32_16x16x32_bf16(qf, kf, (f32x4){0.f, 0.f, 0.f, 0.f}, 0, 0, 0);
    }
    float mx[4], sm[4], inv[4];
#pragma unroll
    for (int j = 0; j < 4; ++j) mx[j] = acc[0][j];
#pragma unroll
    for (int t = 1; t < 32; ++t)
#pragma unroll
      for (int j = 0; j < 4; ++j) mx[j] = fmaxf(mx[j], acc[t][j]);
#pragma unroll
    for (int d = 1; d < 16; d <<= 1)
#pragma unroll
      for (int j = 0; j < 4; ++j) mx[j] = fmaxf(mx[j], __shfl_xor(mx[j], d));
#pragma unroll
    for (int j = 0; j < 4; ++j) sm[j] = 0.f;
#pragma unroll
    for (int t = 0; t < 32; ++t)
#pragma unroll
      for (int j = 0; j < 4; ++j) {
        float p = __builtin_amdgcn_exp2f((acc[t][j] - mx[j]) * CEXP);
        acc[t][j] = p; sm[j] += p;
      }
#pragma unroll
    for (int d = 1; d < 16; d <<= 1)
#pragma unroll
      for (int j = 0; j < 4; ++j) sm[j] += __shfl_xor(sm[j], d);
#pragma unroll
    for (int j = 0; j < 4; ++j) inv[j] = 1.f / sm[j];
    f32x4 o0 = {0.f, 0.f, 0.f, 0.f}, o1 = {0.f, 0.f, 0.f, 0.f};
#pragma unroll
    for (int kk = 0; kk < 16; ++kk) {
#pragma unroll
      for (int tt = 0; tt < 2; ++tt)
#pragma unroll
        for (int j = 0; j < 4; ++j)
          P[wave][hi * 4 + j][tt * 16 + lo] = (bf16)acc[kk * 2 + tt][j];
      bf16x8 pa  = *(const bf16x8*)&P[wave][lo][hi * 8];
      bf16x8 vf0 = *(const bf16x8*)&Vt[lo][kk * 32 + hi * 8];
      bf16x8 vf1 = *(const bf16x8*)&Vt[16 + lo][kk * 32 + hi * 8];
      o0 = __builtin_amdgcn_mfma_f32_16x16x32_bf16(pa, vf0, o0, 0, 0, 0);
      o1 = __builtin_amdgcn_mfma_f32_16x16x32_bf16(pa, vf1, o1, 0, 0, 0);
    }
#pragma unroll
    for (int j = 0; j < 4; ++j) {
      const int s_ = s0 + hi * 4 + j;
      const size_t base = ((size_t)(b_ * SEQ + s_)) * DIM + h_ * DH;
      O[base + lo]      = (bf16)(o0[j] * inv[j]);
      O[base + 16 + lo] = (bf16)(o1[j] * inv[j]);
    }
  }
}

// ---------------- misc kernels ----------------
__global__ __launch_bounds__(256)
void cast_kernel(const float* __restrict__ in, bf16* __restrict__ out) {
  const size_t i = ((size_t)blockIdx.x * 256 + threadIdx.x) * 4;
  const float4 v = *(const float4*)(in + i);
  bf16x4 o;
  o[0] = (bf16)v.x; o[1] = (bf16)v.y; o[2] = (bf16)v.z; o[3] = (bf16)v.w;
  *(bf16x4*)(out + i) = o;
}

// W (L,K,N) f32 -> WT (L,N,K) bf16
__global__ __launch_bounds__(256)
void transpose_cast(const float* __restrict__ W, bf16* __restrict__ WT, int K, int N) {
  __shared__ float t[32][33];
  const int l = blockIdx.z;
  const float* Wl = W + (size_t)l * K * N;
  bf16* WTl = WT + (size_t)l * K * N;
  const int n0 = blockIdx.x * 32, k0 = blockIdx.y * 32;
  const int tx = threadIdx.x, ty = threadIdx.y;
#pragma unroll
  for (int r = 0; r < 32; r += 8)
    t[ty + r][tx] = Wl[(size_t)(k0 + ty + r) * N + n0 + tx];
  __syncthreads();
#pragma unroll
  for (int r = 0; r < 32; r += 8)
    WTl[(size_t)(n0 + ty + r) * K + k0 + tx] = (bf16)t[tx][ty + r];
}

// per-block partial sums for BN: 256 blocks x 64 rows, thread owns 2 channels
__global__ __launch_bounds__(256)
void bn_stats(const bf16* __restrict__ o, const float* __restrict__ x,
              float* __restrict__ part) {
  const int blk = blockIdx.x, tid = threadIdx.x;
  const int c = tid * 2;
  const size_t base = (size_t)blk * 64 * DIM + c;
  float s0 = 0, s1 = 0, q0 = 0, q1 = 0;
  for (int r = 0; r < 64; ++r) {
    const size_t idx = base + (size_t)r * DIM;
    const float2 xv = *(const float2*)(x + idx);
    const bf16x2 ov = *(const bf16x2*)(o + idx);
    const float a = xv.x + (float)ov[0];
    const float b = xv.y + (float)ov[1];
    s0 += a; q0 += a * a; s1 += b; q1 += b * b;
  }
  float4 w = {s0, q0, s1, q1};
  *(float4*)(part + ((size_t)blk * DIM + c) * 2) = w;
}

__global__ __launch_bounds__(256)
void bn_finalize(const float* __restrict__ part, const float* __restrict__ g,
                 const float* __restrict__ be, float* __restrict__ coef) {
  const int c = blockIdx.x * 256 + threadIdx.x;
  float s = 0, q = 0;
  for (int b = 0; b < 256; ++b) {
    const float2 p = *(const float2*)(part + ((size_t)b * DIM + c) * 2);
    s += p.x; q += p.y;
  }
  const float inv_n = 1.f / (float)MTOT;
  const float mean = s * inv_n;
  const float var = q * inv_n - mean * mean;
  const float k = g[c] * rsqrtf(var + 1e-3f);
  coef[c] = k;
  coef[DIM + c] = be[c] - mean * k;
}

// y = (o + x) * k[c] + shift[c]; writes f32 (xout) and optionally bf16 (xbout)
__global__ __launch_bounds__(256)
void bn_apply(const bf16* __restrict__ o, const float* __restrict__ x,
              const float* __restrict__ coef, float* __restrict__ xout,
              bf16* __restrict__ xbout) {
  const size_t i = ((size_t)blockIdx.x * 256 + threadIdx.x) * 4;
  const int c = (int)(i & (DIM - 1));
  const float4 xv = *(const float4*)(x + i);
  const bf16x2 o01 = *(const bf16x2*)(o + i);
  const bf16x2 o23 = *(const bf16x2*)(o + i + 2);
  const float y0 = (xv.x + (float)o01[0]) * coef[c]     + coef[DIM + c];
  const float y1 = (xv.y + (float)o01[1]) * coef[c + 1] + coef[DIM + c + 1];
  const float y2 = (xv.z + (float)o23[0]) * coef[c + 2] + coef[DIM + c + 2];
  const float y3 = (xv.w + (float)o23[1]) * coef[c + 3] + coef[DIM + c + 3];
  float4 yo = {y0, y1, y2, y3};
  *(float4*)(xout + i) = yo;
  if (xbout) {
    bf16x4 yb;
    yb[0] = (bf16)y0; yb[1] = (bf16)y1; yb[2] = (bf16)y2; yb[3] = (bf16)y3;
    *(bf16x4*)(xbout + i) = yb;
  }
}

// ---------------- workspace offsets (bytes) ----------------
#define OFF_XB   ((size_t)0)
#define OFF_Q    ((size_t)16777216)
#define OFF_K    ((size_t)33554432)
#define OFF_V    ((size_t)50331648)
#define OFF_O    ((size_t)67108864)
#define OFF_H    ((size_t)16777216)   // aliases Q/K/V/O region (dead by FF1)
#define OFF_Z    ((size_t)83886080)
#define OFF_X    ((size_t)100663296)
#define OFF_WQT  ((size_t)134217728)
#define OFF_WKT  ((size_t)135790592)
#define OFF_WVT  ((size_t)137363456)
#define OFF_W1T  ((size_t)138936320)
#define OFF_W2T  ((size_t)145227776)
#define OFF_PART ((size_t)151519232)
#define OFF_COEF ((size_t)152567808)

extern "C" void kernel_launch(void* const* d_in, const int* in_sizes, int n_in,
                              void* d_out, int out_size, void* d_ws, size_t ws_size,
                              hipStream_t stream) {
  const float* x_in = (const float*)d_in[0];
  const float* Wq = (const float*)d_in[1];
  const float* bq = (const float*)d_in[2];
  const float* Wk = (const float*)d_in[3];
  const float* bk = (const float*)d_in[4];
  const float* Wv = (const float*)d_in[5];
  const float* bv = (const float*)d_in[6];
  const float* g1 = (const float*)d_in[7];
  const float* be1 = (const float*)d_in[8];
  const float* W1 = (const float*)d_in[9];
  const float* b1 = (const float*)d_in[10];
  const float* W2 = (const float*)d_in[11];
  const float* b2 = (const float*)d_in[12];
  const float* g2 = (const float*)d_in[13];
  const float* be2 = (const float*)d_in[14];
  float* out = (float*)d_out;

  char* ws = (char*)d_ws;
  bf16* xb   = (bf16*)(ws + OFF_XB);
  bf16* qb   = (bf16*)(ws + OFF_Q);
  bf16* kb   = (bf16*)(ws + OFF_K);
  bf16* vb   = (bf16*)(ws + OFF_V);
  bf16* ob   = (bf16*)(ws + OFF_O);
  bf16* hb   = (bf16*)(ws + OFF_H);
  bf16* zb   = (bf16*)(ws + OFF_Z);
  float* xf  = (float*)(ws + OFF_X);
  bf16* wqT  = (bf16*)(ws + OFF_WQT);
  bf16* wkT  = (bf16*)(ws + OFF_WKT);
  bf16* wvT  = (bf16*)(ws + OFF_WVT);
  bf16* w1T  = (bf16*)(ws + OFF_W1T);
  bf16* w2T  = (bf16*)(ws + OFF_W2T);
  float* part = (float*)(ws + OFF_PART);
  float* coef = (float*)(ws + OFF_COEF);

  const dim3 blk32(32, 8);
  transpose_cast<<<dim3(16, 16, 3), blk32, 0, stream>>>(Wq, wqT, 512, 512);
  transpose_cast<<<dim3(16, 16, 3), blk32, 0, stream>>>(Wk, wkT, 512, 512);
  transpose_cast<<<dim3(16, 16, 3), blk32, 0, stream>>>(Wv, wvT, 512, 512);
  transpose_cast<<<dim3(64, 16, 3), blk32, 0, stream>>>(W1, w1T, 512, 2048);
  transpose_cast<<<dim3(16, 64, 3), blk32, 0, stream>>>(W2, w2T, 2048, 512);
  cast_kernel<<<8192, 256, 0, stream>>>(x_in, xb);

  for (int l = 0; l < 3; ++l) {
    const float* xcur = (l == 0) ? x_in : xf;
    gemm_bt<0><<<dim3(4, 128), 256, 0, stream>>>(xb, wqT + (size_t)l * 512 * 512, bq + l * 512, qb, 512, 512);
    gemm_bt<0><<<dim3(4, 128), 256, 0, stream>>>(xb, wkT + (size_t)l * 512 * 512, bk + l * 512, kb, 512, 512);
    gemm_bt<0><<<dim3(4, 128), 256, 0, stream>>>(xb, wvT + (size_t)l * 512 * 512, bv + l * 512, vb, 512, 512);
    attn_kernel<<<512, 256, 0, stream>>>(qb, kb, vb, ob);
    bn_stats<<<256, 256, 0, stream>>>(ob, xcur, part);
    bn_finalize<<<2, 256, 0, stream>>>(part, g1 + l * 512, be1 + l * 512, coef);
    bn_apply<<<8192, 256, 0, stream>>>(ob, xcur, coef, xf, xb);
    gemm_bt<1><<<dim3(16, 128), 256, 0, stream>>>(xb, w1T + (size_t)l * 2048 * 512, b1 + l * 2048, hb, 2048, 512);
    gemm_bt<2><<<dim3(4, 128), 256, 0, stream>>>(hb, w2T + (size_t)l * 512 * 2048, b2 + l * 512, zb, 512, 2048);
    bn_stats<<<256, 256, 0, stream>>>(zb, xf, part);
    bn_finalize<<<2, 256, 0, stream>>>(part, g2 + l * 512, be2 + l * 512, coef);
    if (l < 2)
      bn_apply<<<8192, 256, 0, stream>>>(zb, xf, coef, xf, xb);
    else
      bn_apply<<<8192, 256, 0, stream>>>(zb, xf, coef, out, (bf16*)nullptr);
  }
}